// Round 8
// baseline (189.231 us; speedup 1.0000x reference)
//
#include <hip/hip_runtime.h>
#include <hip/hip_bf16.h>

typedef __bf16 bf16x8 __attribute__((ext_vector_type(8)));
typedef float  f32x4  __attribute__((ext_vector_type(4)));

constexpr int B = 8, N = 4096, T = 128, D = 32;
constexpr float GAMMA = 0.001f;
constexpr float LOG2E = 1.4426950408889634f;
constexpr float K2 = -GAMMA * LOG2E;   // coeff on sq1 / sq2 (log2 domain)
constexpr float M2 = -2.0f * K2;       // coeff on dot

#define AS1C(p) ((const __attribute__((address_space(1))) void*)(p))
#define AS3P(p) ((__attribute__((address_space(3))) void*)(p))

__device__ __forceinline__ float exp2_fast(float t) {
#if __has_builtin(__builtin_amdgcn_exp2f)
  return __builtin_amdgcn_exp2f(t);
#else
  return exp2f(t);
#endif
}

// deg-3 minimax for 2^t on [-2, 0]; abs err ~6.5e-4 (t provably in-range).
__device__ __forceinline__ float exp2_poly(float t) {
  return fmaf(fmaf(fmaf(0.0285860f, t, 0.2107500f), t, 0.6821055f), t,
              0.9993455f);
}

// ---------------------------------------------------------------------------
// Kernel 1 (MFMA proj): unchanged from r3-r7 (~5-8 us).
// ---------------------------------------------------------------------------
__global__ __launch_bounds__(256, 2) void proj_mfma(
    const float* __restrict__ x,  const float* __restrict__ W1,
    const float* __restrict__ b1, const float* __restrict__ W2,
    const float* __restrict__ b2,
    __bf16* __restrict__ p1b, __bf16* __restrict__ p2b,
    float* __restrict__ s1, float* __restrict__ e2) {
  __shared__ bf16x8 wlds[4][4][64];   // 16 KB, frag-ready
  const int tid  = threadIdx.x;
  const int lane = tid & 63;
  const int wid  = tid >> 6;
  const int lr   = lane & 15;
  const int lk   = lane >> 4;
  const int r0   = blockIdx.x * 64 + wid * 16;   // 0 .. B*N-1

  #pragma unroll
  for (int t = 0; t < 4; ++t) {
    const int e  = tid + t * 256;
    const int c  = e >> 8;
    const int s  = (e >> 6) & 3;
    const int ln = e & 63;
    const int llr = ln & 15, llk = ln >> 4;
    const float* Wp = (c < 2) ? W1 : W2;
    const int cc = (c * 16 + llr) & 31;
    bf16x8 v;
    #pragma unroll
    for (int j = 0; j < 8; ++j)
      v[j] = (__bf16)Wp[(s * 32 + llk * 8 + j) * D + cc];
    wlds[c][s][ln] = v;
  }
  __syncthreads();

  bf16x8 wf[4][4];
  #pragma unroll
  for (int c = 0; c < 4; ++c)
    #pragma unroll
    for (int s = 0; s < 4; ++s)
      wf[c][s] = wlds[c][s][lane];

  bf16x8 af[4];
  const float* xr = x + (size_t)(r0 + lr) * T;
  #pragma unroll
  for (int s = 0; s < 4; ++s) {
    const int t0 = s * 32 + lk * 8;
    const f32x4 v0 = *reinterpret_cast<const f32x4*>(xr + t0);
    const f32x4 v1 = *reinterpret_cast<const f32x4*>(xr + t0 + 4);
    #pragma unroll
    for (int j = 0; j < 4; ++j) {
      af[s][j]     = (__bf16)v0[j];
      af[s][4 + j] = (__bf16)v1[j];
    }
  }

  f32x4 pv[4];
  #pragma unroll
  for (int c = 0; c < 4; ++c) {
    const float* bp = (c < 2) ? b1 : b2;
    const float bv = bp[(c * 16 + lr) & 31];
    f32x4 accv = {bv, bv, bv, bv};
    #pragma unroll
    for (int s = 0; s < 4; ++s)
      accv = __builtin_amdgcn_mfma_f32_16x16x32_bf16(af[s], wf[c][s], accv, 0, 0, 0);
    pv[c] = accv;
  }

  #pragma unroll
  for (int c = 0; c < 2; ++c)
    #pragma unroll
    for (int r = 0; r < 4; ++r)
      p1b[(size_t)(r0 + lk * 4 + r) * D + c * 16 + lr] = (__bf16)(M2 * pv[c][r]);
  #pragma unroll
  for (int c = 2; c < 4; ++c)
    #pragma unroll
    for (int r = 0; r < 4; ++r)
      p2b[(size_t)(r0 + lk * 4 + r) * D + (c - 2) * 16 + lr] = (__bf16)pv[c][r];

  float q1[4], q2[4];
  #pragma unroll
  for (int r = 0; r < 4; ++r) {
    q1[r] = fmaf(pv[0][r], pv[0][r], pv[1][r] * pv[1][r]);
    q2[r] = fmaf(pv[2][r], pv[2][r], pv[3][r] * pv[3][r]);
  }
  #pragma unroll
  for (int m = 1; m < 16; m <<= 1)
    #pragma unroll
    for (int r = 0; r < 4; ++r) {
      q1[r] += __shfl_xor(q1[r], m, 64);
      q2[r] += __shfl_xor(q2[r], m, 64);
    }
  if (lr == 0) {
    #pragma unroll
    for (int r = 0; r < 4; ++r) {
      const int row = r0 + lk * 4 + r;
      s1[row] = K2 * q1[r];
      e2[row] = 0.125f * exp2_fast(K2 * q2[r]);
    }
  }
}

// ---------------------------------------------------------------------------
// Kernel 2 v8: LDS double-buffered batch pipeline via global_load_lds.
// Theory: r1-r7 invariant ~40us floor = per-wave VMEM latency exposure with
// low effective occupancy. stage(b+1) is fire-and-forget DMA overlapped with
// compute(b); __syncthreads drains vmcnt. LDS rows are 64B; frag ds_read_b128
// would be 8-way bank conflicted, so reads XOR slot with (row>>1)&3 and the
// DMA's GLOBAL source address is inverse-swizzled per lane (LDS dest linear,
// rule #21: both-sides-or-neither).
// ---------------------------------------------------------------------------
struct Tile {
  __bf16 A[128 * 32];   // 8 KB (swizzled slots)
  __bf16 Bt[64 * 32];   // 4 KB (swizzled slots)
  float  S[128];        // 512 B
  float  E[64];         // 256 B
};

__global__ __launch_bounds__(256, 4) void fused_kernel(
    const __bf16* __restrict__ p1b, const __bf16* __restrict__ p2b,
    const float* __restrict__ s1,   const float* __restrict__ e2,
    float* __restrict__ out) {
  __shared__ __align__(16) Tile tiles[2];

  const int lane = threadIdx.x & 63;
  const int wid  = threadIdx.x >> 6;
  const int j0 = blockIdx.x * 64;                // col base (block)
  const int i0blk = blockIdx.y * 128;            // row base (block)
  const int i0 = i0blk + wid * 32;               // row base (wave)
  const int lr = lane & 15;
  const int lk = lane >> 4;

  f32x4 acc[2][4];
  #pragma unroll
  for (int a = 0; a < 2; ++a)
    #pragma unroll
    for (int c = 0; c < 4; ++c)
      acc[a][c] = f32x4{0.f, 0.f, 0.f, 0.f};

  auto stage = [&](Tile& t, int b) __attribute__((always_inline)) {
    const char* gA = (const char*)(p1b + ((size_t)b * N + i0blk) * D);
    const char* gB = (const char*)(p2b + ((size_t)b * N + j0) * D);
    // A: 8KB, each wave 2 x 1KB DMA (dest = uniform base + lane*16)
    #pragma unroll
    for (int q = 0; q < 2; ++q) {
      const int L   = wid * 2048 + q * 1024 + lane * 16;
      const int row = L >> 6;
      const int su  = ((L >> 4) & 3) ^ ((row >> 1) & 3);
      __builtin_amdgcn_global_load_lds(AS1C(gA + row * 64 + su * 16),
          AS3P((char*)t.A + wid * 2048 + q * 1024), 16, 0, 0);
    }
    // B: 4KB, each wave 1 x 1KB
    {
      const int L   = wid * 1024 + lane * 16;
      const int row = L >> 6;
      const int su  = ((L >> 4) & 3) ^ ((row >> 1) & 3);
      __builtin_amdgcn_global_load_lds(AS1C(gB + row * 64 + su * 16),
          AS3P((char*)t.Bt + wid * 1024), 16, 0, 0);
    }
    // S: 512B by wave 0 (2 x 256B width-4); E: 256B by wave 1
    if (wid == 0) {
      #pragma unroll
      for (int q = 0; q < 2; ++q)
        __builtin_amdgcn_global_load_lds(
            AS1C(s1 + (size_t)b * N + i0blk + q * 64 + lane),
            AS3P((char*)t.S + q * 256), 4, 0, 0);
    } else if (wid == 1) {
      __builtin_amdgcn_global_load_lds(AS1C(e2 + (size_t)b * N + j0 + lane),
                                       AS3P((char*)t.E), 4, 0, 0);
    }
  };

  auto compute = [&](const Tile& t) __attribute__((always_inline)) {
    f32x4 S[2];
    #pragma unroll
    for (int a = 0; a < 2; ++a)
      S[a] = *reinterpret_cast<const f32x4*>(&t.S[wid * 32 + a * 16 + lk * 4]);
    float E[4];
    #pragma unroll
    for (int c = 0; c < 4; ++c)
      E[c] = t.E[c * 16 + lr];
    bf16x8 A[2];
    #pragma unroll
    for (int a = 0; a < 2; ++a) {
      const int ra = wid * 32 + a * 16 + lr;
      const int su = lk ^ ((ra >> 1) & 3);
      A[a] = *reinterpret_cast<const bf16x8*>((const char*)t.A + ra * 64 + su * 16);
    }
    bf16x8 Bf[4];
    #pragma unroll
    for (int c = 0; c < 4; ++c) {
      const int rb = c * 16 + lr;
      const int su = lk ^ ((rb >> 1) & 3);
      Bf[c] = *reinterpret_cast<const bf16x8*>((const char*)t.Bt + rb * 64 + su * 16);
    }
    #pragma unroll
    for (int a = 0; a < 2; ++a) {
      #pragma unroll
      for (int c = 0; c < 4; ++c) {
        f32x4 tt = __builtin_amdgcn_mfma_f32_16x16x32_bf16(
            A[a], Bf[c], S[a], 0, 0, 0);
        #pragma unroll
        for (int r = 0; r < 4; ++r)
          acc[a][c][r] = fmaf(E[c], exp2_poly(tt[r]), acc[a][c][r]);
      }
    }
  };

  stage(tiles[0], 0);
  #pragma unroll
  for (int b = 0; b < B; ++b) {
    __syncthreads();                 // drains vmcnt: tiles[b&1] ready; prior reads done
    if (b + 1 < B) stage(tiles[(b + 1) & 1], b + 1);
    compute(tiles[b & 1]);
  }

  const bool hasdiag = (i0 < j0 + 64) && (j0 < i0 + 32);
  #pragma unroll
  for (int a = 0; a < 2; ++a) {
    #pragma unroll
    for (int c = 0; c < 4; ++c) {
      #pragma unroll
      for (int r = 0; r < 4; ++r) {
        const int row = i0 + a * 16 + lk * 4 + r;
        const int col = j0 + c * 16 + lr;
        float v = acc[a][c][r];
        if (hasdiag && row == col) v = 0.1f;
        out[(size_t)row * N + col] = v;
      }
    }
  }
}

extern "C" void kernel_launch(void* const* d_in, const int* in_sizes, int n_in,
                              void* d_out, int out_size, void* d_ws, size_t ws_size,
                              hipStream_t stream) {
  (void)in_sizes; (void)n_in; (void)out_size; (void)ws_size;
  const float* x  = (const float*)d_in[0];
  const float* W1 = (const float*)d_in[1];
  const float* b1 = (const float*)d_in[2];
  const float* W2 = (const float*)d_in[3];
  const float* b2 = (const float*)d_in[4];
  float* out = (float*)d_out;

  char* ws = (char*)d_ws;
  const size_t pbytes = (size_t)B * N * D * sizeof(__bf16);  // 2 MB each
  __bf16* p1b = (__bf16*)ws;
  __bf16* p2b = (__bf16*)(ws + pbytes);
  float*  s1  = (float*)(ws + 2 * pbytes);
  float*  e2  = (float*)(ws + 2 * pbytes + (size_t)B * N * sizeof(float));

  proj_mfma<<<(B * N) / 64, 256, 0, stream>>>(x, W1, b1, W2, b2, p1b, p2b, s1, e2);

  dim3 grid(N / 64, N / 128);
  fused_kernel<<<grid, 256, 0, stream>>>(p1b, p2b, s1, e2, out);
}

// Round 9
// 37.330 us; speedup vs baseline: 5.0692x; 5.0692x over previous
//
#include <hip/hip_runtime.h>
#include <hip/hip_bf16.h>

typedef __bf16 bf16x8 __attribute__((ext_vector_type(8)));
typedef float  f32x4  __attribute__((ext_vector_type(4)));

constexpr int B = 8, N = 4096, T = 128, D = 32;
constexpr float GAMMA = 0.001f;
constexpr float LOG2E = 1.4426950408889634f;
constexpr float K2 = -GAMMA * LOG2E;   // coeff on sq1 / sq2 (log2 domain)
constexpr float M2 = -2.0f * K2;       // coeff on dot

__device__ __forceinline__ float exp2_fast(float t) {
#if __has_builtin(__builtin_amdgcn_exp2f)
  return __builtin_amdgcn_exp2f(t);
#else
  return exp2f(t);
#endif
}

// deg-3 minimax for 2^t on [-2, 0]; abs err ~6.5e-4 (t provably in-range).
__device__ __forceinline__ float exp2_poly(float t) {
  return fmaf(fmaf(fmaf(0.0285860f, t, 0.2107500f), t, 0.6821055f), t,
              0.9993455f);
}

// ---------------------------------------------------------------------------
// Kernel 1 (MFMA proj): unchanged from r3-r7 (~2 us).
// ---------------------------------------------------------------------------
__global__ __launch_bounds__(256, 2) void proj_mfma(
    const float* __restrict__ x,  const float* __restrict__ W1,
    const float* __restrict__ b1, const float* __restrict__ W2,
    const float* __restrict__ b2,
    __bf16* __restrict__ p1b, __bf16* __restrict__ p2b,
    float* __restrict__ s1, float* __restrict__ e2) {
  __shared__ bf16x8 wlds[4][4][64];   // 16 KB, frag-ready
  const int tid  = threadIdx.x;
  const int lane = tid & 63;
  const int wid  = tid >> 6;
  const int lr   = lane & 15;
  const int lk   = lane >> 4;
  const int r0   = blockIdx.x * 64 + wid * 16;   // 0 .. B*N-1

  #pragma unroll
  for (int t = 0; t < 4; ++t) {
    const int e  = tid + t * 256;
    const int c  = e >> 8;
    const int s  = (e >> 6) & 3;
    const int ln = e & 63;
    const int llr = ln & 15, llk = ln >> 4;
    const float* Wp = (c < 2) ? W1 : W2;
    const int cc = (c * 16 + llr) & 31;
    bf16x8 v;
    #pragma unroll
    for (int j = 0; j < 8; ++j)
      v[j] = (__bf16)Wp[(s * 32 + llk * 8 + j) * D + cc];
    wlds[c][s][ln] = v;
  }
  __syncthreads();

  bf16x8 wf[4][4];
  #pragma unroll
  for (int c = 0; c < 4; ++c)
    #pragma unroll
    for (int s = 0; s < 4; ++s)
      wf[c][s] = wlds[c][s][lane];

  bf16x8 af[4];
  const float* xr = x + (size_t)(r0 + lr) * T;
  #pragma unroll
  for (int s = 0; s < 4; ++s) {
    const int t0 = s * 32 + lk * 8;
    const f32x4 v0 = *reinterpret_cast<const f32x4*>(xr + t0);
    const f32x4 v1 = *reinterpret_cast<const f32x4*>(xr + t0 + 4);
    #pragma unroll
    for (int j = 0; j < 4; ++j) {
      af[s][j]     = (__bf16)v0[j];
      af[s][4 + j] = (__bf16)v1[j];
    }
  }

  f32x4 pv[4];
  #pragma unroll
  for (int c = 0; c < 4; ++c) {
    const float* bp = (c < 2) ? b1 : b2;
    const float bv = bp[(c * 16 + lr) & 31];
    f32x4 accv = {bv, bv, bv, bv};
    #pragma unroll
    for (int s = 0; s < 4; ++s)
      accv = __builtin_amdgcn_mfma_f32_16x16x32_bf16(af[s], wf[c][s], accv, 0, 0, 0);
    pv[c] = accv;
  }

  #pragma unroll
  for (int c = 0; c < 2; ++c)
    #pragma unroll
    for (int r = 0; r < 4; ++r)
      p1b[(size_t)(r0 + lk * 4 + r) * D + c * 16 + lr] = (__bf16)(M2 * pv[c][r]);
  #pragma unroll
  for (int c = 2; c < 4; ++c)
    #pragma unroll
    for (int r = 0; r < 4; ++r)
      p2b[(size_t)(r0 + lk * 4 + r) * D + (c - 2) * 16 + lr] = (__bf16)pv[c][r];

  float q1[4], q2[4];
  #pragma unroll
  for (int r = 0; r < 4; ++r) {
    q1[r] = fmaf(pv[0][r], pv[0][r], pv[1][r] * pv[1][r]);
    q2[r] = fmaf(pv[2][r], pv[2][r], pv[3][r] * pv[3][r]);
  }
  #pragma unroll
  for (int m = 1; m < 16; m <<= 1)
    #pragma unroll
    for (int r = 0; r < 4; ++r) {
      q1[r] += __shfl_xor(q1[r], m, 64);
      q2[r] += __shfl_xor(q2[r], m, 64);
    }
  if (lr == 0) {
    #pragma unroll
    for (int r = 0; r < 4; ++r) {
      const int row = r0 + lk * 4 + r;
      s1[row] = K2 * q1[r];
      e2[row] = 0.125f * exp2_fast(K2 * q2[r]);
    }
  }
}

// ---------------------------------------------------------------------------
// Kernel 2 v9: ALL global reads up front (before the store storm thrashes
// L2), then pure LDS/register compute, then stores.
//  - A-fragments for all 8 batches in registers (statically indexed).
//  - B/S/E for all 8 batches in 38 KB LDS; B rows XOR-swizzled
//    (slot ^= (row>>1)&3) -> ds_read_b128 is conflict-free (bijective
//    per 1KB block); swizzle applied on BOTH write and read (rule #21).
//  - Theory: r1-r7's ~40us wall = per-iter loads L2-missing (write-stream
//    thrash) at ~900cy latency, MLP 12 too shallow. Phase-1 has ~30
//    independent VMEM/thread -> one amortized drain.
// ---------------------------------------------------------------------------
__global__ __launch_bounds__(256, 3) void fused_kernel(
    const __bf16* __restrict__ p1b, const __bf16* __restrict__ p2b,
    const float* __restrict__ s1,   const float* __restrict__ e2,
    float* __restrict__ out) {
  __shared__ __align__(16) __bf16 LB[B * 64 * 32];  // 32 KB, swizzled slots
  __shared__ __align__(16) float  LS[B * 128];      // 4 KB
  __shared__ __align__(16) float  LE[B * 64];       // 2 KB

  const int tid  = threadIdx.x;
  const int lane = tid & 63;
  const int wid  = tid >> 6;
  const int j0 = blockIdx.x * 64;                // col base (block)
  const int i0blk = blockIdx.y * 128;            // row base (block)
  const int i0 = i0blk + wid * 32;               // row base (wave)
  const int lr = lane & 15;
  const int lk = lane >> 4;

  // ---- phase 1: stage EVERYTHING (deep MLP, no stores in flight yet) ----
  // B tiles -> LDS (swizzled): 2048 16B-chunks, 8 per thread
  #pragma unroll
  for (int q = 0; q < 8; ++q) {
    const int g   = tid + q * 256;
    const int b   = g >> 8;
    const int c8  = g & 255;
    const int row = c8 >> 2;
    const int sl  = c8 & 3;
    const bf16x8 v = *reinterpret_cast<const bf16x8*>(
        p2b + ((size_t)b * N + j0 + row) * D + sl * 8);
    const int su = sl ^ ((row >> 1) & 3);
    *reinterpret_cast<bf16x8*>(&LB[(((b << 6) + row) << 2 | su) << 3]) = v;
  }
  // S -> LDS: 1024 floats, one f32x4 per thread
  {
    const int b = tid >> 5, o = (tid & 31) * 4;
    *reinterpret_cast<f32x4*>(&LS[b * 128 + o]) =
        *reinterpret_cast<const f32x4*>(s1 + (size_t)b * N + i0blk + o);
  }
  // E -> LDS: 512 floats, threads 0-127
  if (tid < 128) {
    const int b = tid >> 4, o = (tid & 15) * 4;
    *reinterpret_cast<f32x4*>(&LE[b * 64 + o]) =
        *reinterpret_cast<const f32x4*>(e2 + (size_t)b * N + j0 + o);
  }
  // A-fragments for all batches -> registers (64 VGPR)
  bf16x8 Areg[B][2];
  #pragma unroll
  for (int b = 0; b < B; ++b)
    #pragma unroll
    for (int a = 0; a < 2; ++a)
      Areg[b][a] = *reinterpret_cast<const bf16x8*>(
          p1b + ((size_t)b * N + i0 + a * 16 + lr) * D + lk * 8);

  __syncthreads();

  // ---- phase 2: pure LDS/register compute ----
  f32x4 acc[2][4];
  #pragma unroll
  for (int a = 0; a < 2; ++a)
    #pragma unroll
    for (int c = 0; c < 4; ++c)
      acc[a][c] = f32x4{0.f, 0.f, 0.f, 0.f};

  const int sub = lk ^ ((lr >> 1) & 3);   // B-read swizzle (c*16 keeps bits)
  #pragma unroll
  for (int b = 0; b < B; ++b) {
    bf16x8 Bf[4];
    #pragma unroll
    for (int c = 0; c < 4; ++c)
      Bf[c] = *reinterpret_cast<const bf16x8*>(
          &LB[(((b << 6) + c * 16 + lr) << 2 | sub) << 3]);
    f32x4 S[2];
    #pragma unroll
    for (int a = 0; a < 2; ++a)
      S[a] = *reinterpret_cast<const f32x4*>(
          &LS[b * 128 + wid * 32 + a * 16 + lk * 4]);
    float E[4];
    #pragma unroll
    for (int c = 0; c < 4; ++c)
      E[c] = LE[b * 64 + c * 16 + lr];

    #pragma unroll
    for (int a = 0; a < 2; ++a) {
      #pragma unroll
      for (int c = 0; c < 4; ++c) {
        f32x4 t = __builtin_amdgcn_mfma_f32_16x16x32_bf16(
            Areg[b][a], Bf[c], S[a], 0, 0, 0);
        #pragma unroll
        for (int r = 0; r < 4; ++r)
          acc[a][c][r] = fmaf(E[c], exp2_poly(t[r]), acc[a][c][r]);
      }
    }
  }

  // ---- phase 3: stores ----
  const bool hasdiag = (i0 < j0 + 64) && (j0 < i0 + 32);
  #pragma unroll
  for (int a = 0; a < 2; ++a) {
    #pragma unroll
    for (int c = 0; c < 4; ++c) {
      #pragma unroll
      for (int r = 0; r < 4; ++r) {
        const int row = i0 + a * 16 + lk * 4 + r;
        const int col = j0 + c * 16 + lr;
        float v = acc[a][c][r];
        if (hasdiag && row == col) v = 0.1f;
        out[(size_t)row * N + col] = v;
      }
    }
  }
}

extern "C" void kernel_launch(void* const* d_in, const int* in_sizes, int n_in,
                              void* d_out, int out_size, void* d_ws, size_t ws_size,
                              hipStream_t stream) {
  (void)in_sizes; (void)n_in; (void)out_size; (void)ws_size;
  const float* x  = (const float*)d_in[0];
  const float* W1 = (const float*)d_in[1];
  const float* b1 = (const float*)d_in[2];
  const float* W2 = (const float*)d_in[3];
  const float* b2 = (const float*)d_in[4];
  float* out = (float*)d_out;

  char* ws = (char*)d_ws;
  const size_t pbytes = (size_t)B * N * D * sizeof(__bf16);  // 2 MB each
  __bf16* p1b = (__bf16*)ws;
  __bf16* p2b = (__bf16*)(ws + pbytes);
  float*  s1  = (float*)(ws + 2 * pbytes);
  float*  e2  = (float*)(ws + 2 * pbytes + (size_t)B * N * sizeof(float));

  proj_mfma<<<(B * N) / 64, 256, 0, stream>>>(x, W1, b1, W2, b2, p1b, p2b, s1, e2);

  dim3 grid(N / 64, N / 128);
  fused_kernel<<<grid, 256, 0, stream>>>(p1b, p2b, s1, e2, out);
}